// Round 1
// baseline (494.981 us; speedup 1.0000x reference)
//
#include <hip/hip_runtime.h>

#define N_NODES 100000
#define N_EDGES 640000
#define IN_F 256
#define HD 128   // HEADS * OUT_FEATS

// ---------------- GEMM: C[M,128] = A[M,256] * W[256,128] (f32) ----------------
__global__ __launch_bounds__(256) void gemm_f32(const float* __restrict__ A,
    const float* __restrict__ B, float* __restrict__ C, int M)
{
  __shared__ float As[128][33];   // +1 pad: ty-groups land on distinct banks
  __shared__ float Bs[32][128];
  const int t = threadIdx.x;
  const int tx = t & 15, ty = t >> 4;
  const int rowBase = blockIdx.x * 128;
  float acc[8][8];
  #pragma unroll
  for (int i = 0; i < 8; i++)
    #pragma unroll
    for (int j = 0; j < 8; j++) acc[i][j] = 0.f;

  for (int k0 = 0; k0 < IN_F; k0 += 32) {
    #pragma unroll
    for (int i = 0; i < 4; i++) {
      int q = t + i * 256;
      int r = q >> 3, c4 = q & 7;
      int gr = rowBase + r; if (gr > M - 1) gr = M - 1;  // clamp tail loads
      const float4 va = *(const float4*)(A + (size_t)gr * IN_F + k0 + c4 * 4);
      As[r][c4 * 4 + 0] = va.x; As[r][c4 * 4 + 1] = va.y;
      As[r][c4 * 4 + 2] = va.z; As[r][c4 * 4 + 3] = va.w;
    }
    #pragma unroll
    for (int i = 0; i < 4; i++) {
      int q = t + i * 256;
      int br = q >> 5, bc = q & 31;
      *(float4*)(&Bs[br][bc * 4]) = *(const float4*)(B + (size_t)(k0 + br) * HD + bc * 4);
    }
    __syncthreads();
    #pragma unroll
    for (int k = 0; k < 32; k++) {
      float av[8];
      #pragma unroll
      for (int i = 0; i < 8; i++) av[i] = As[ty * 8 + i][k];
      const float4 b0 = *(const float4*)(&Bs[k][tx * 4]);
      const float4 b1 = *(const float4*)(&Bs[k][64 + tx * 4]);
      #pragma unroll
      for (int i = 0; i < 8; i++) {
        acc[i][0] += av[i] * b0.x; acc[i][1] += av[i] * b0.y;
        acc[i][2] += av[i] * b0.z; acc[i][3] += av[i] * b0.w;
        acc[i][4] += av[i] * b1.x; acc[i][5] += av[i] * b1.y;
        acc[i][6] += av[i] * b1.z; acc[i][7] += av[i] * b1.w;
      }
    }
    __syncthreads();
  }
  #pragma unroll
  for (int i = 0; i < 8; i++) {
    int r = rowBase + ty * 8 + i;
    if (r < M) {
      float4 o0 = make_float4(acc[i][0], acc[i][1], acc[i][2], acc[i][3]);
      float4 o1 = make_float4(acc[i][4], acc[i][5], acc[i][6], acc[i][7]);
      *(float4*)(C + (size_t)r * HD + tx * 4) = o0;
      *(float4*)(C + (size_t)r * HD + 64 + tx * 4) = o1;
    }
  }
}

// ---------------- per-node logits el/er: one wave per node ----------------
__global__ __launch_bounds__(256) void elr_kernel(const float* __restrict__ ft,
    const float* __restrict__ al, const float* __restrict__ ar,
    float* __restrict__ el, float* __restrict__ er, int n)
{
  int v = blockIdx.x * 4 + (threadIdx.x >> 6);
  if (v >= n) return;
  int lane = threadIdx.x & 63;
  float f0 = ft[(size_t)v * HD + lane], f1 = ft[(size_t)v * HD + 64 + lane];
  float l0 = f0 * al[lane],      l1 = f1 * al[64 + lane];
  float r0 = f0 * ar[lane],      r1 = f1 * ar[64 + lane];
  #pragma unroll
  for (int off = 16; off >= 1; off >>= 1) {
    l0 += __shfl_xor(l0, off); l1 += __shfl_xor(l1, off);
    r0 += __shfl_xor(r0, off); r1 += __shfl_xor(r1, off);
  }
  if ((lane & 31) == 0) {
    int g = lane >> 5;  // lanes 0-31: heads {0,2}; lanes 32-63: heads {1,3}
    el[v * 4 + g] = l0; el[v * 4 + 2 + g] = l1;
    er[v * 4 + g] = r0; er[v * 4 + 2 + g] = r1;
  }
}

// ---------------- CSR build ----------------
__global__ void deg_kernel(const int* __restrict__ dst, int* __restrict__ deg) {
  int i = blockIdx.x * blockDim.x + threadIdx.x;
  if (i < N_EDGES) atomicAdd(&deg[dst[i]], 1);
}

__global__ __launch_bounds__(256) void scanA(const int* __restrict__ deg,
    int* __restrict__ excl, int* __restrict__ partials, int n)
{
  __shared__ int s[256];
  int t = threadIdx.x;
  int base = blockIdx.x * 1024 + t * 4;
  int d0 = (base + 0 < n) ? deg[base + 0] : 0;
  int d1 = (base + 1 < n) ? deg[base + 1] : 0;
  int d2 = (base + 2 < n) ? deg[base + 2] : 0;
  int d3 = (base + 3 < n) ? deg[base + 3] : 0;
  int sum = d0 + d1 + d2 + d3;
  s[t] = sum; __syncthreads();
  for (int off = 1; off < 256; off <<= 1) {
    int x = 0; if (t >= off) x = s[t - off];
    __syncthreads(); s[t] += x; __syncthreads();
  }
  int e0 = s[t] - sum;
  if (base + 0 < n) excl[base + 0] = e0;
  if (base + 1 < n) excl[base + 1] = e0 + d0;
  if (base + 2 < n) excl[base + 2] = e0 + d0 + d1;
  if (base + 3 < n) excl[base + 3] = e0 + d0 + d1 + d2;
  if (t == 255) partials[blockIdx.x] = s[255];
}

__global__ void scanB(int* partials, int nb) {
  __shared__ int s[128];
  int t = threadIdx.x;
  int v = (t < nb) ? partials[t] : 0;
  s[t] = v; __syncthreads();
  for (int off = 1; off < 128; off <<= 1) {
    int x = 0; if (t >= off) x = s[t - off];
    __syncthreads(); s[t] += x; __syncthreads();
  }
  if (t < nb) partials[t] = s[t] - v;  // exclusive
}

__global__ __launch_bounds__(256) void scanC(int* __restrict__ row_ptr,
    const int* __restrict__ partials, int n, int E)
{
  int t = threadIdx.x;
  int base = blockIdx.x * 1024 + t * 4;
  int add = partials[blockIdx.x];
  #pragma unroll
  for (int j = 0; j < 4; j++) if (base + j < n) row_ptr[base + j] += add;
  if (blockIdx.x == 0 && t == 0) row_ptr[n] = E;
}

__global__ void scatter_kernel(const int* __restrict__ dst, const int* __restrict__ row_ptr,
                               int* __restrict__ cursor, int* __restrict__ eid) {
  int e = blockIdx.x * blockDim.x + threadIdx.x;
  if (e >= N_EDGES) return;
  int d = dst[e];
  int pos = row_ptr[d] + atomicAdd(&cursor[d], 1);
  eid[pos] = e;
}

// ---------------- fused softmax + aggregation: one wave per dst node ----------------
__global__ __launch_bounds__(256) void gat_node(const int* __restrict__ row_ptr,
    const int* __restrict__ eid, const int* __restrict__ src,
    const float* __restrict__ el, const float* __restrict__ er4,
    const float* __restrict__ ft, float* __restrict__ rst, float* __restrict__ a_out,
    float* __restrict__ denom, int n)
{
  int v = blockIdx.x * 4 + (threadIdx.x >> 6);
  if (v >= n) return;
  int lane = threadIdx.x & 63;
  int s0 = row_ptr[v], s1 = row_ptr[v + 1];
  int d = s1 - s0;
  if (d == 0) {
    rst[(size_t)v * HD + lane] = 0.f;
    rst[(size_t)v * HD + 64 + lane] = 0.f;
    return;
  }
  const float4 erv = *(const float4*)(er4 + (size_t)v * 4);
  // pass 1: per-head max over incoming edges (lanes parallel over edges)
  float m0 = -1e30f, m1 = -1e30f, m2 = -1e30f, m3 = -1e30f;
  for (int j = lane; j < d; j += 64) {
    int e = eid[s0 + j];
    int u = src[e];
    const float4 elv = *(const float4*)(el + (size_t)u * 4);
    float x0 = elv.x + erv.x; x0 = x0 > 0.f ? x0 : 0.2f * x0;
    float x1 = elv.y + erv.y; x1 = x1 > 0.f ? x1 : 0.2f * x1;
    float x2 = elv.z + erv.z; x2 = x2 > 0.f ? x2 : 0.2f * x2;
    float x3 = elv.w + erv.w; x3 = x3 > 0.f ? x3 : 0.2f * x3;
    m0 = fmaxf(m0, x0); m1 = fmaxf(m1, x1); m2 = fmaxf(m2, x2); m3 = fmaxf(m3, x3);
  }
  #pragma unroll
  for (int off = 32; off >= 1; off >>= 1) {
    m0 = fmaxf(m0, __shfl_xor(m0, off));
    m1 = fmaxf(m1, __shfl_xor(m1, off));
    m2 = fmaxf(m2, __shfl_xor(m2, off));
    m3 = fmaxf(m3, __shfl_xor(m3, off));
  }
  // pass 2: serial over edges; every lane computes all 4 head scalars (broadcast loads)
  float den0 = 0, den1 = 0, den2 = 0, den3 = 0;
  float acc0 = 0.f, acc1 = 0.f;
  int g = lane >> 5;  // col lane -> head g; col lane+64 -> head 2+g
  for (int j = 0; j < d; j++) {
    int e = eid[s0 + j];
    int u = src[e];
    const float4 elv = *(const float4*)(el + (size_t)u * 4);
    float x0 = elv.x + erv.x; x0 = x0 > 0.f ? x0 : 0.2f * x0; float ex0 = __expf(x0 - m0); den0 += ex0;
    float x1 = elv.y + erv.y; x1 = x1 > 0.f ? x1 : 0.2f * x1; float ex1 = __expf(x1 - m1); den1 += ex1;
    float x2 = elv.z + erv.z; x2 = x2 > 0.f ? x2 : 0.2f * x2; float ex2 = __expf(x2 - m2); den2 += ex2;
    float x3 = elv.w + erv.w; x3 = x3 > 0.f ? x3 : 0.2f * x3; float ex3 = __expf(x3 - m3); den3 += ex3;
    if (lane < 4) {
      float exs = lane == 0 ? ex0 : lane == 1 ? ex1 : lane == 2 ? ex2 : ex3;
      a_out[(size_t)e * 4 + lane] = exs;   // unnormalized; norm_kernel divides later
    }
    float fa = ft[(size_t)u * HD + lane];
    float fb = ft[(size_t)u * HD + 64 + lane];
    acc0 += (g ? ex1 : ex0) * fa;
    acc1 += (g ? ex3 : ex2) * fb;
  }
  float da = g ? den1 : den0;
  float db = g ? den3 : den2;
  rst[(size_t)v * HD + lane]      = acc0 / da;
  rst[(size_t)v * HD + 64 + lane] = acc1 / db;
  if (lane < 4) {
    float dn = lane == 0 ? den0 : lane == 1 ? den1 : lane == 2 ? den2 : den3;
    denom[(size_t)v * 4 + lane] = dn;
  }
}

__global__ void norm_kernel(const int* __restrict__ dst, const float* __restrict__ denom,
                            float* __restrict__ a, int E) {
  int i = blockIdx.x * blockDim.x + threadIdx.x;
  if (i >= E) return;
  int d = dst[i];
  float4 v = *(float4*)(a + (size_t)i * 4);
  const float4 dn = *(const float4*)(denom + (size_t)d * 4);
  v.x /= dn.x; v.y /= dn.y; v.z /= dn.z; v.w /= dn.w;
  *(float4*)(a + (size_t)i * 4) = v;
}

extern "C" void kernel_launch(void* const* d_in, const int* in_sizes, int n_in,
                              void* d_out, int out_size, void* d_ws, size_t ws_size,
                              hipStream_t stream)
{
  const float* feat = (const float*)d_in[0];
  const float* W    = (const float*)d_in[1];
  const float* al   = (const float*)d_in[2];
  const float* ar   = (const float*)d_in[3];
  const int*   src  = (const int*)d_in[4];
  const int*   dst  = (const int*)d_in[5];
  float* rst   = (float*)d_out;
  float* a_out = rst + (size_t)N_NODES * HD;

  char* w = (char*)d_ws;
  auto alloc = [&](size_t bytes) { char* p = w; w += (bytes + 255) & ~(size_t)255; return p; };
  float* ft      = (float*)alloc((size_t)N_NODES * HD * 4);
  float* el      = (float*)alloc((size_t)N_NODES * 4 * 4);
  float* er      = (float*)alloc((size_t)N_NODES * 4 * 4);
  float* denom   = (float*)alloc((size_t)N_NODES * 4 * 4);
  int*   deg     = (int*)alloc((size_t)N_NODES * 4);
  int*   row_ptr = (int*)alloc(((size_t)N_NODES + 1) * 4);
  int*   cursor  = (int*)alloc((size_t)N_NODES * 4);
  int*   partials= (int*)alloc(1024);
  int*   eid     = (int*)alloc((size_t)N_EDGES * 4);

  hipMemsetAsync(deg, 0, N_NODES * 4, stream);
  hipMemsetAsync(cursor, 0, N_NODES * 4, stream);

  gemm_f32<<<(N_NODES + 127) / 128, 256, 0, stream>>>(feat, W, ft, N_NODES);
  elr_kernel<<<(N_NODES + 3) / 4, 256, 0, stream>>>(ft, al, ar, el, er, N_NODES);
  deg_kernel<<<(N_EDGES + 255) / 256, 256, 0, stream>>>(dst, deg);
  scanA<<<98, 256, 0, stream>>>(deg, row_ptr, partials, N_NODES);
  scanB<<<1, 128, 0, stream>>>(partials, 98);
  scanC<<<98, 256, 0, stream>>>(row_ptr, partials, N_NODES, N_EDGES);
  scatter_kernel<<<(N_EDGES + 255) / 256, 256, 0, stream>>>(dst, row_ptr, cursor, eid);
  gat_node<<<(N_NODES + 3) / 4, 256, 0, stream>>>(row_ptr, eid, src, el, er, ft, rst, a_out, denom, N_NODES);
  norm_kernel<<<(N_EDGES + 255) / 256, 256, 0, stream>>>(dst, denom, a_out, N_EDGES);
}

// Round 2
// 404.305 us; speedup vs baseline: 1.2243x; 1.2243x over previous
//
#include <hip/hip_runtime.h>

#define N_NODES 100000
#define N_EDGES 640000
#define IN_F 256
#define HD 128   // HEADS * OUT_FEATS

// ---------------- GEMM: C[M,128] = A[M,256] * W[256,128] (f32) ----------------
__global__ __launch_bounds__(256) void gemm_f32(const float* __restrict__ A,
    const float* __restrict__ B, float* __restrict__ C, int M)
{
  __shared__ float As[128][33];
  __shared__ float Bs[32][128];
  const int t = threadIdx.x;
  const int tx = t & 15, ty = t >> 4;
  const int rowBase = blockIdx.x * 128;
  float acc[8][8];
  #pragma unroll
  for (int i = 0; i < 8; i++)
    #pragma unroll
    for (int j = 0; j < 8; j++) acc[i][j] = 0.f;

  for (int k0 = 0; k0 < IN_F; k0 += 32) {
    #pragma unroll
    for (int i = 0; i < 4; i++) {
      int q = t + i * 256;
      int r = q >> 3, c4 = q & 7;
      int gr = rowBase + r; if (gr > M - 1) gr = M - 1;
      const float4 va = *(const float4*)(A + (size_t)gr * IN_F + k0 + c4 * 4);
      As[r][c4 * 4 + 0] = va.x; As[r][c4 * 4 + 1] = va.y;
      As[r][c4 * 4 + 2] = va.z; As[r][c4 * 4 + 3] = va.w;
    }
    #pragma unroll
    for (int i = 0; i < 4; i++) {
      int q = t + i * 256;
      int br = q >> 5, bc = q & 31;
      *(float4*)(&Bs[br][bc * 4]) = *(const float4*)(B + (size_t)(k0 + br) * HD + bc * 4);
    }
    __syncthreads();
    #pragma unroll
    for (int k = 0; k < 32; k++) {
      float av[8];
      #pragma unroll
      for (int i = 0; i < 8; i++) av[i] = As[ty * 8 + i][k];
      const float4 b0 = *(const float4*)(&Bs[k][tx * 4]);
      const float4 b1 = *(const float4*)(&Bs[k][64 + tx * 4]);
      #pragma unroll
      for (int i = 0; i < 8; i++) {
        acc[i][0] += av[i] * b0.x; acc[i][1] += av[i] * b0.y;
        acc[i][2] += av[i] * b0.z; acc[i][3] += av[i] * b0.w;
        acc[i][4] += av[i] * b1.x; acc[i][5] += av[i] * b1.y;
        acc[i][6] += av[i] * b1.z; acc[i][7] += av[i] * b1.w;
      }
    }
    __syncthreads();
  }
  #pragma unroll
  for (int i = 0; i < 8; i++) {
    int r = rowBase + ty * 8 + i;
    if (r < M) {
      float4 o0 = make_float4(acc[i][0], acc[i][1], acc[i][2], acc[i][3]);
      float4 o1 = make_float4(acc[i][4], acc[i][5], acc[i][6], acc[i][7]);
      *(float4*)(C + (size_t)r * HD + tx * 4) = o0;
      *(float4*)(C + (size_t)r * HD + 64 + tx * 4) = o1;
    }
  }
}

// ---------------- per-node logits el/er: one wave per node ----------------
__global__ __launch_bounds__(256) void elr_kernel(const float* __restrict__ ft,
    const float* __restrict__ al, const float* __restrict__ ar,
    float* __restrict__ el, float* __restrict__ er, int n)
{
  int v = blockIdx.x * 4 + (threadIdx.x >> 6);
  if (v >= n) return;
  int lane = threadIdx.x & 63;
  float f0 = ft[(size_t)v * HD + lane], f1 = ft[(size_t)v * HD + 64 + lane];
  float l0 = f0 * al[lane],      l1 = f1 * al[64 + lane];
  float r0 = f0 * ar[lane],      r1 = f1 * ar[64 + lane];
  #pragma unroll
  for (int off = 16; off >= 1; off >>= 1) {
    l0 += __shfl_xor(l0, off); l1 += __shfl_xor(l1, off);
    r0 += __shfl_xor(r0, off); r1 += __shfl_xor(r1, off);
  }
  if ((lane & 31) == 0) {
    int g = lane >> 5;
    el[v * 4 + g] = l0; el[v * 4 + 2 + g] = l1;
    er[v * 4 + g] = r0; er[v * 4 + 2 + g] = r1;
  }
}

// ---------------- CSR build ----------------
__global__ void deg_kernel(const int* __restrict__ dst, int* __restrict__ deg) {
  int i = blockIdx.x * blockDim.x + threadIdx.x;
  if (i < N_EDGES) atomicAdd(&deg[dst[i]], 1);
}

__global__ __launch_bounds__(256) void scanA(const int* __restrict__ deg,
    int* __restrict__ excl, int* __restrict__ partials, int n)
{
  __shared__ int s[256];
  int t = threadIdx.x;
  int base = blockIdx.x * 1024 + t * 4;
  int d0 = (base + 0 < n) ? deg[base + 0] : 0;
  int d1 = (base + 1 < n) ? deg[base + 1] : 0;
  int d2 = (base + 2 < n) ? deg[base + 2] : 0;
  int d3 = (base + 3 < n) ? deg[base + 3] : 0;
  int sum = d0 + d1 + d2 + d3;
  s[t] = sum; __syncthreads();
  for (int off = 1; off < 256; off <<= 1) {
    int x = 0; if (t >= off) x = s[t - off];
    __syncthreads(); s[t] += x; __syncthreads();
  }
  int e0 = s[t] - sum;
  if (base + 0 < n) excl[base + 0] = e0;
  if (base + 1 < n) excl[base + 1] = e0 + d0;
  if (base + 2 < n) excl[base + 2] = e0 + d0 + d1;
  if (base + 3 < n) excl[base + 3] = e0 + d0 + d1 + d2;
  if (t == 255) partials[blockIdx.x] = s[255];
}

__global__ void scanB(int* partials, int nb) {
  __shared__ int s[128];
  int t = threadIdx.x;
  int v = (t < nb) ? partials[t] : 0;
  s[t] = v; __syncthreads();
  for (int off = 1; off < 128; off <<= 1) {
    int x = 0; if (t >= off) x = s[t - off];
    __syncthreads(); s[t] += x; __syncthreads();
  }
  if (t < nb) partials[t] = s[t] - v;
}

__global__ __launch_bounds__(256) void scanC(int* __restrict__ row_ptr,
    const int* __restrict__ partials, int n, int E)
{
  int t = threadIdx.x;
  int base = blockIdx.x * 1024 + t * 4;
  int add = partials[blockIdx.x];
  #pragma unroll
  for (int j = 0; j < 4; j++) if (base + j < n) row_ptr[base + j] += add;
  if (blockIdx.x == 0 && t == 0) row_ptr[n] = E;
}

// scatter: store SRC NODE IDS in CSR order (no eid indirection downstream)
__global__ void scatter_kernel(const int* __restrict__ src, const int* __restrict__ dst,
                               const int* __restrict__ row_ptr,
                               int* __restrict__ cursor, int* __restrict__ usrc) {
  int e = blockIdx.x * blockDim.x + threadIdx.x;
  if (e >= N_EDGES) return;
  int d = dst[e];
  int pos = row_ptr[d] + atomicAdd(&cursor[d], 1);
  usrc[pos] = src[e];
}

// ---------------- fused online-softmax + aggregation: one wave per dst node ----------------
__global__ __launch_bounds__(256) void gat_node(const int* __restrict__ row_ptr,
    const int* __restrict__ usrc,
    const float* __restrict__ el, const float* __restrict__ er4,
    const float* __restrict__ ft, float* __restrict__ rst,
    float* __restrict__ lse, int n)
{
  __shared__ int   su[4][64];
  __shared__ float sex[4][64][4];
  const int w = threadIdx.x >> 6;
  const int lane = threadIdx.x & 63;
  const int v = blockIdx.x * 4 + w;
  if (v >= n) return;
  const int s0 = row_ptr[v];
  const int d  = row_ptr[v + 1] - s0;
  const int g  = lane >> 4;   // head owning columns 2*lane, 2*lane+1

  if (d == 0) {
    *(float2*)(rst + (size_t)v * HD + 2 * lane) = make_float2(0.f, 0.f);
    return;
  }

  const float4 erv = *(const float4*)(er4 + (size_t)v * 4);
  float m0 = -1e30f, m1 = -1e30f, m2 = -1e30f, m3 = -1e30f;
  float den = 0.f;
  float2 acc = make_float2(0.f, 0.f);

  for (int c0 = 0; c0 < d; c0 += 64) {
    const int cd = min(64, d - c0);
    // phase A: lane-parallel logits for this chunk (coalesced usrc read)
    float x0 = -1e30f, x1 = -1e30f, x2 = -1e30f, x3 = -1e30f;
    int u = 0;
    if (lane < cd) {
      u = usrc[s0 + c0 + lane];
      const float4 elv = *(const float4*)(el + (size_t)u * 4);
      x0 = elv.x + erv.x; x0 = x0 > 0.f ? x0 : 0.2f * x0;
      x1 = elv.y + erv.y; x1 = x1 > 0.f ? x1 : 0.2f * x1;
      x2 = elv.z + erv.z; x2 = x2 > 0.f ? x2 : 0.2f * x2;
      x3 = elv.w + erv.w; x3 = x3 > 0.f ? x3 : 0.2f * x3;
    }
    su[w][lane] = u;
    // chunk max, combined with running max
    float n0 = x0, n1 = x1, n2 = x2, n3 = x3;
    #pragma unroll
    for (int off = 32; off >= 1; off >>= 1) {
      n0 = fmaxf(n0, __shfl_xor(n0, off));
      n1 = fmaxf(n1, __shfl_xor(n1, off));
      n2 = fmaxf(n2, __shfl_xor(n2, off));
      n3 = fmaxf(n3, __shfl_xor(n3, off));
    }
    n0 = fmaxf(n0, m0); n1 = fmaxf(n1, m1); n2 = fmaxf(n2, m2); n3 = fmaxf(n3, m3);
    // per-lane exp (inactive lanes give exp(-1e30 - n) == 0)
    float e0 = __expf(x0 - n0), e1 = __expf(x1 - n1);
    float e2 = __expf(x2 - n2), e3 = __expf(x3 - n3);
    sex[w][lane][0] = e0; sex[w][lane][1] = e1;
    sex[w][lane][2] = e2; sex[w][lane][3] = e3;
    // rescale running accumulators for this lane's head
    float mg = g == 0 ? m0 : g == 1 ? m1 : g == 2 ? m2 : m3;
    float ng = g == 0 ? n0 : g == 1 ? n1 : g == 2 ? n2 : n3;
    float scale = __expf(mg - ng);
    den *= scale; acc.x *= scale; acc.y *= scale;
    m0 = n0; m1 = n1; m2 = n2; m3 = n3;
    // drain the wave's own LDS writes before cross-lane reads (no barrier needed:
    // each wave owns its su/sex slice)
    asm volatile("s_waitcnt lgkmcnt(0)" ::: "memory");
    // phase B: serial over chunk edges; addresses come from LDS, ft loads independent
    #pragma unroll 4
    for (int j = 0; j < cd; ++j) {
      int uu = su[w][j];
      float wgt = sex[w][j][g];
      float2 f = *(const float2*)(ft + (size_t)uu * HD + 2 * lane);
      den += wgt;
      acc.x += wgt * f.x; acc.y += wgt * f.y;
    }
  }
  *(float2*)(rst + (size_t)v * HD + 2 * lane) = make_float2(acc.x / den, acc.y / den);
  if ((lane & 15) == 0) {
    float mg = g == 0 ? m0 : g == 1 ? m1 : g == 2 ? m2 : m3;
    lse[(size_t)v * 4 + g] = mg + __logf(den);
  }
}

// edge-parallel: a[e][h] = exp(leaky(el[src]+er[dst]) - lse[dst][h])
__global__ void norm_kernel(const int* __restrict__ src, const int* __restrict__ dst,
                            const float* __restrict__ el, const float* __restrict__ er,
                            const float* __restrict__ lse, float* __restrict__ a, int E)
{
  int i = blockIdx.x * blockDim.x + threadIdx.x;
  if (i >= E) return;
  int u = src[i], v = dst[i];
  const float4 elv = *(const float4*)(el + (size_t)u * 4);
  const float4 erv = *(const float4*)(er + (size_t)v * 4);
  const float4 ls  = *(const float4*)(lse + (size_t)v * 4);
  float x0 = elv.x + erv.x; x0 = x0 > 0.f ? x0 : 0.2f * x0;
  float x1 = elv.y + erv.y; x1 = x1 > 0.f ? x1 : 0.2f * x1;
  float x2 = elv.z + erv.z; x2 = x2 > 0.f ? x2 : 0.2f * x2;
  float x3 = elv.w + erv.w; x3 = x3 > 0.f ? x3 : 0.2f * x3;
  float4 o;
  o.x = __expf(x0 - ls.x); o.y = __expf(x1 - ls.y);
  o.z = __expf(x2 - ls.z); o.w = __expf(x3 - ls.w);
  *(float4*)(a + (size_t)i * 4) = o;
}

extern "C" void kernel_launch(void* const* d_in, const int* in_sizes, int n_in,
                              void* d_out, int out_size, void* d_ws, size_t ws_size,
                              hipStream_t stream)
{
  const float* feat = (const float*)d_in[0];
  const float* W    = (const float*)d_in[1];
  const float* al   = (const float*)d_in[2];
  const float* ar   = (const float*)d_in[3];
  const int*   src  = (const int*)d_in[4];
  const int*   dst  = (const int*)d_in[5];
  float* rst   = (float*)d_out;
  float* a_out = rst + (size_t)N_NODES * HD;

  char* w = (char*)d_ws;
  auto alloc = [&](size_t bytes) { char* p = w; w += (bytes + 255) & ~(size_t)255; return p; };
  float* ft      = (float*)alloc((size_t)N_NODES * HD * 4);
  float* el      = (float*)alloc((size_t)N_NODES * 4 * 4);
  float* er      = (float*)alloc((size_t)N_NODES * 4 * 4);
  float* lse     = (float*)alloc((size_t)N_NODES * 4 * 4);
  int*   deg     = (int*)alloc((size_t)N_NODES * 4);
  int*   row_ptr = (int*)alloc(((size_t)N_NODES + 1) * 4);
  int*   cursor  = (int*)alloc((size_t)N_NODES * 4);
  int*   partials= (int*)alloc(1024);
  int*   usrc    = (int*)alloc((size_t)N_EDGES * 4);

  hipMemsetAsync(deg, 0, N_NODES * 4, stream);
  hipMemsetAsync(cursor, 0, N_NODES * 4, stream);

  gemm_f32<<<(N_NODES + 127) / 128, 256, 0, stream>>>(feat, W, ft, N_NODES);
  elr_kernel<<<(N_NODES + 3) / 4, 256, 0, stream>>>(ft, al, ar, el, er, N_NODES);
  deg_kernel<<<(N_EDGES + 255) / 256, 256, 0, stream>>>(dst, deg);
  scanA<<<98, 256, 0, stream>>>(deg, row_ptr, partials, N_NODES);
  scanB<<<1, 128, 0, stream>>>(partials, 98);
  scanC<<<98, 256, 0, stream>>>(row_ptr, partials, N_NODES, N_EDGES);
  scatter_kernel<<<(N_EDGES + 255) / 256, 256, 0, stream>>>(src, dst, row_ptr, cursor, usrc);
  gat_node<<<(N_NODES + 3) / 4, 256, 0, stream>>>(row_ptr, usrc, el, er, ft, rst, lse, N_NODES);
  norm_kernel<<<(N_EDGES + 255) / 256, 256, 0, stream>>>(src, dst, el, er, lse, a_out, N_EDGES);
}